// Round 8
// baseline (1085.868 us; speedup 1.0000x reference)
//
#include <hip/hip_runtime.h>
#include <hip/hip_fp16.h>

// GCN R11: one-dispatch fused pipeline (R10 phase bodies, all verified as
// standalone kernels in R8/R5) with the launch machinery made failure-proof:
// regular launch + software grid barrier (device-scope atomics + threadfence,
// the documented XCD-safe release/acquire pattern). Grid sized from a cached
// hipOccupancy query with an 8-CU margin -> all blocks provably co-resident,
// barrier cannot deadlock. All strides use gridDim.x.

#define N_NODES 50000
#define N_EDGES 800000
#define KDIM 256
#define BK 32
#define ELLCAP 64

typedef __attribute__((ext_vector_type(8))) short short8;
typedef __attribute__((ext_vector_type(4))) float f32x4;

__device__ __forceinline__ ushort f2bf(float f) {
    union { float f; unsigned u; } x; x.f = f;
    unsigned r = x.u + 0x7fffu + ((x.u >> 16) & 1u);  // RTN-even
    return (ushort)(r >> 16);
}
__device__ __forceinline__ float bf2f(ushort u) {
    union { unsigned u; float f; } x; x.u = ((unsigned)u) << 16;
    return x.f;
}

__device__ __forceinline__ void gld_lds16(const void* g, void* l) {
    __builtin_amdgcn_global_load_lds(
        (const __attribute__((address_space(1))) void*)g,
        (__attribute__((address_space(3))) void*)l, 16, 0, 0);
}

// ---- software grid barrier: bar[0]=arrive count, bar[1]=generation --------
__device__ __forceinline__ void gsync(unsigned* bar) {
    __syncthreads();
    if (threadIdx.x == 0) {
        __threadfence();   // release: L2 writeback, prior stores visible
        unsigned nb = gridDim.x;
        unsigned g = __hip_atomic_load(&bar[1], __ATOMIC_RELAXED,
                                       __HIP_MEMORY_SCOPE_AGENT);
        unsigned a = __hip_atomic_fetch_add(&bar[0], 1u, __ATOMIC_ACQ_REL,
                                            __HIP_MEMORY_SCOPE_AGENT);
        if (a == nb - 1) {
            __hip_atomic_store(&bar[0], 0u, __ATOMIC_RELAXED,
                               __HIP_MEMORY_SCOPE_AGENT);
            __hip_atomic_fetch_add(&bar[1], 1u, __ATOMIC_RELEASE,
                                   __HIP_MEMORY_SCOPE_AGENT);
        } else {
            while (__hip_atomic_load(&bar[1], __ATOMIC_ACQUIRE,
                                     __HIP_MEMORY_SCOPE_AGENT) == g)
                __builtin_amdgcn_s_sleep(2);
        }
        __threadfence();   // acquire: invalidate caches before phase reads
    }
    __syncthreads();
}

// ---------------- gemm 64x256 tile phase (verified R8 body) ---------------
// A dbuf 2x4KB @0, B dbuf 2x16KB @8192 -> 40960B total.
__device__ void gemm256_phase(char* smem, const ushort* __restrict__ A,
                              const ushort* __restrict__ Wt,
                              ushort* __restrict__ C) {
    const int M = N_NODES;
    int t = threadIdx.x, lane = t & 63, w = t >> 6;
    int q = lane >> 4, mi = lane & 15;
    int wn = w * 64;

    for (int tile = blockIdx.x; tile < 782; tile += gridDim.x) {
        int row0 = tile * 64;

        auto stageA = [&](int bi, int k0) {
            char* dst = smem + bi * 4096;
            int g = t;                       // 256 granules
            int row = row0 + ((g >> 6) << 4) + (g & 15);
            if (row >= M) row = M - 1;
            const ushort* src = A + (size_t)row * KDIM + k0 + (((g & 63) >> 4) << 3);
            gld_lds16(src, dst + (w * 64) * 16);
        };
        auto stageB = [&](int bi, int k0) {
            char* dst = smem + 8192 + bi * 16384;
            #pragma unroll
            for (int i = 0; i < 4; i++) {    // 1024 granules
                int g = i * 256 + t;
                int col = ((g >> 6) << 4) + (g & 15);
                const ushort* src = Wt + (size_t)col * KDIM + k0 + (((g & 63) >> 4) << 3);
                gld_lds16(src, dst + (i * 256 + w * 64) * 16);
            }
        };

        f32x4 acc[4][4];
        #pragma unroll
        for (int i = 0; i < 4; i++)
            #pragma unroll
            for (int j = 0; j < 4; j++) acc[i][j] = (f32x4)0.f;

        stageA(0, 0);
        stageB(0, 0);
        __syncthreads();

        #pragma unroll
        for (int kt = 0; kt < 8; kt++) {
            int cur = kt & 1;
            if (kt < 7) {
                stageA(cur ^ 1, (kt + 1) * BK);
                stageB(cur ^ 1, (kt + 1) * BK);
            }
            const char* Ac = smem + cur * 4096;
            const char* Bc = smem + 8192 + cur * 16384;

            short8 af[4], bfr[4];
            #pragma unroll
            for (int mt = 0; mt < 4; mt++)
                af[mt] = *(const short8*)(Ac + (mt * 64 + lane) * 16);
            #pragma unroll
            for (int nt = 0; nt < 4; nt++)
                bfr[nt] = *(const short8*)(Bc + ((w * 4 + nt) * 64 + lane) * 16);

            #pragma unroll
            for (int mt = 0; mt < 4; mt++)
                #pragma unroll
                for (int nt = 0; nt < 4; nt++)
                    acc[mt][nt] = __builtin_amdgcn_mfma_f32_16x16x32_bf16(
                        af[mt], bfr[nt], acc[mt][nt], 0, 0, 0);

            __syncthreads();
        }

        ushort* Cs = (ushort*)smem;          // 64x256 bf16 = 32KB
        #pragma unroll
        for (int mt = 0; mt < 4; mt++)
            #pragma unroll
            for (int r = 0; r < 4; r++)
                #pragma unroll
                for (int nt = 0; nt < 4; nt++)
                    Cs[(mt * 16 + q * 4 + r) * 256 + wn + nt * 16 + mi] =
                        f2bf(acc[mt][nt][r]);
        __syncthreads();
        #pragma unroll
        for (int i = 0; i < 8; i++) {        // 2048 granules of 16B
            int idx = i * 256 + t;
            int rr = idx >> 5, gc = idx & 31;
            int grow = row0 + rr;
            if (grow < M)
                *(short8*)&C[(size_t)grow * 256 + gc * 8] =
                    *(const short8*)&Cs[rr * 256 + gc * 8];
        }
        __syncthreads();                     // Cs reuse guard for next tile
    }
}

// ---------------- gemm 128x128 tile phase (verified R5 body) --------------
__device__ void gemm128_phase(char* smem, const ushort* __restrict__ A,
                              const ushort* __restrict__ Wt,
                              ushort* __restrict__ C) {
    const int M = N_NODES, N = 128;
    int t = threadIdx.x, lane = t & 63, w = t >> 6;
    int wbase = w * 64;
    int wm2 = w & 1, wn2 = w >> 1;
    int wm = wm2 * 64, wn = wn2 * 64;
    int q = lane >> 4, mi = lane & 15;

    for (int tile = blockIdx.x; tile < 391; tile += gridDim.x) {
        int row0 = tile * 128;
        char* Ab0 = smem;
        char* Ab1 = smem + 8192;
        char* Bb0 = smem + 16384;
        char* Bb1 = smem + 24576;

        auto stageA = [&](char* dst, int k0) {
            #pragma unroll
            for (int i = 0; i < 2; i++) {
                int D = i * 256 + t;
                int f = D >> 6, lp = D & 63;
                int row = row0 + (f >> 2) * 64 + (f & 3) * 16 + (lp & 15);
                if (row >= M) row = M - 1;
                const ushort* g = A + (size_t)row * KDIM + k0 + (lp >> 4) * 8;
                gld_lds16(g, dst + (i * 256 + wbase) * 16);
            }
        };
        auto stageB = [&](char* dst, int k0) {
            #pragma unroll
            for (int i = 0; i < 2; i++) {
                int D = i * 256 + t;
                int f = D >> 6, lp = D & 63;
                int col = (f >> 2) * 64 + (f & 3) * 16 + (lp & 15);
                const ushort* g = Wt + (size_t)col * KDIM + k0 + (lp >> 4) * 8;
                gld_lds16(g, dst + (i * 256 + wbase) * 16);
            }
        };

        f32x4 acc[4][4];
        #pragma unroll
        for (int i = 0; i < 4; i++)
            #pragma unroll
            for (int j = 0; j < 4; j++) acc[i][j] = (f32x4)0.f;

        stageA(Ab0, 0);
        stageB(Bb0, 0);
        __syncthreads();

        #pragma unroll
        for (int kt = 0; kt < 8; kt++) {
            char* Acur = (kt & 1) ? Ab1 : Ab0;
            char* Bcur = (kt & 1) ? Bb1 : Bb0;
            if (kt < 7) {
                stageA((kt & 1) ? Ab0 : Ab1, (kt + 1) * BK);
                stageB((kt & 1) ? Bb0 : Bb1, (kt + 1) * BK);
            }
            short8 af[4], bfr[4];
            #pragma unroll
            for (int mt = 0; mt < 4; mt++)
                af[mt] = *(const short8*)(Acur + ((wm2 * 4 + mt) * 64 + lane) * 16);
            #pragma unroll
            for (int nt = 0; nt < 4; nt++)
                bfr[nt] = *(const short8*)(Bcur + ((wn2 * 4 + nt) * 64 + lane) * 16);

            #pragma unroll
            for (int mt = 0; mt < 4; mt++)
                #pragma unroll
                for (int nt = 0; nt < 4; nt++)
                    acc[mt][nt] = __builtin_amdgcn_mfma_f32_16x16x32_bf16(
                        af[mt], bfr[nt], acc[mt][nt], 0, 0, 0);

            __syncthreads();
        }

        ushort* Cs = (ushort*)smem;          // 128x128 bf16 = 32KB
        #pragma unroll
        for (int mt = 0; mt < 4; mt++)
            #pragma unroll
            for (int r = 0; r < 4; r++)
                #pragma unroll
                for (int nt = 0; nt < 4; nt++)
                    Cs[(wm + mt * 16 + q * 4 + r) * N + wn + nt * 16 + mi] =
                        f2bf(acc[mt][nt][r]);
        __syncthreads();
        #pragma unroll
        for (int i = 0; i < 8; i++) {
            int idx = i * 256 + t;
            int rr = idx >> 4, gc = idx & 15;
            int grow = row0 + rr;
            if (grow < M)
                *(short8*)&C[(size_t)grow * N + gc * 8] =
                    *(const short8*)&Cs[rr * N + gc * 8];
        }
        __syncthreads();
    }
}

// ---------------- spmm phase (verified R8 body, grid-strided) -------------
template <int F, bool RELU, bool OUT_BF16>
__device__ void spmm_phase(const ushort* __restrict__ H,
                           const int* __restrict__ cnt,
                           const unsigned* __restrict__ cvp,
                           const float* __restrict__ bias,
                           void* __restrict__ out) {
    constexpr int FL = F / 8;
    constexpr int EP = 64 / FL;
    constexpr int STEP = EP * 8;
    int wave = threadIdx.x >> 6, lane = threadIdx.x & 63;
    int fl = lane % FL, ep = lane / FL;
    const ushort* Hl = H + fl * 8;

    for (int rb = blockIdx.x; rb < 12500; rb += gridDim.x) {
        int r = rb * 4 + wave;               // < 50000 always

        float acc[8];
        #pragma unroll
        for (int j = 0; j < 8; j++) acc[j] = 0.f;

        int start = r << 6;
        int end = start + cnt[r];
        for (int base = start; base < end; base += STEP) {
            int e0 = base + ep * 8;
            uint4 ma = *(const uint4*)&cvp[e0];
            uint4 mb = *(const uint4*)&cvp[e0 + 4];
            unsigned mw[8] = {ma.x, ma.y, ma.z, ma.w, mb.x, mb.y, mb.z, mb.w};
            int   c[8];
            float v[8];
            #pragma unroll
            for (int u = 0; u < 8; u++) {
                bool ok = (e0 + u < end);
                c[u] = ok ? (int)(mw[u] >> 16) : 0;
                v[u] = ok ? __half2float(__ushort_as_half((ushort)mw[u])) : 0.f;
            }
            short8 h[8];
            #pragma unroll
            for (int u = 0; u < 8; u++)
                h[u] = *(const short8*)&Hl[(size_t)c[u] * F];
            #pragma unroll
            for (int j = 0; j < 8; j++) {
                #pragma unroll
                for (int u = 0; u < 8; u++)
                    acc[j] += v[u] * bf2f((ushort)h[u][j]);
            }
        }

        #pragma unroll
        for (int off = FL; off < 64; off <<= 1)
            #pragma unroll
            for (int j = 0; j < 8; j++) acc[j] += __shfl_down(acc[j], off, 64);

        if (ep == 0) {
            #pragma unroll
            for (int j = 0; j < 8; j++) {
                float o = acc[j] + bias[fl * 8 + j];
                if (RELU) o = fmaxf(o, 0.f);
                acc[j] = o;
            }
            if (OUT_BF16) {
                short8 ob;
                #pragma unroll
                for (int j = 0; j < 8; j++) ob[j] = (short)f2bf(acc[j]);
                *(short8*)((ushort*)out + (size_t)r * F + fl * 8) = ob;
            } else {
                float* of = (float*)out + (size_t)r * F + fl * 8;
                *(float4*)&of[0] = make_float4(acc[0], acc[1], acc[2], acc[3]);
                *(float4*)&of[4] = make_float4(acc[4], acc[5], acc[6], acc[7]);
            }
        }
    }
}

// ---------------- the fused kernel ----------------------------------------
__global__ __launch_bounds__(256, 3) void fused_gcn(
        const float* __restrict__ x, const float* __restrict__ vals,
        const int* __restrict__ rows, const int* __restrict__ cols,
        const float* __restrict__ W1, const float* __restrict__ b1,
        const float* __restrict__ W2, const float* __restrict__ b2,
        const float* __restrict__ W3, const float* __restrict__ b3,
        float* __restrict__ out, ushort* __restrict__ bufG,
        ushort* __restrict__ bufH, ushort* __restrict__ Wt1,
        ushort* __restrict__ Wt2, ushort* __restrict__ Wt3,
        int* __restrict__ cnt, unsigned* __restrict__ cvp,
        unsigned* __restrict__ bar) {
    __shared__ char smem[40960];

    int b = blockIdx.x, t = threadIdx.x;
    int nthr = gridDim.x << 8;
    int gid = (b << 8) + t;

    // ---- p0: zero cnt + weight transpose-casts (grid-stride) ----
    for (int id = gid; id < 50048; id += nthr) cnt[id] = 0;
    for (int id = gid; id < 163840; id += nthr) {
        if (id < 65536) {
            int n = id >> 8, k = id & 255;
            Wt1[n * 256 + k] = f2bf(W1[k * 256 + n]);
        } else if (id < 131072) {
            int i = id - 65536, n = i >> 8, k = i & 255;
            Wt2[n * 256 + k] = f2bf(W2[k * 256 + n]);
        } else {
            int i = id - 131072, n = i >> 8, k = i & 255;
            Wt3[n * 256 + k] = f2bf(W3[k * 128 + n]);
        }
    }
    gsync(bar);

    // ---- p1: ELL build (first third of blocks) || x->bf16 cast (rest) ----
    int EB = gridDim.x / 3;
    if (b < EB) {
        for (int o = gid; o < N_EDGES / 8; o += (EB << 8)) {
            int e0 = o * 8;
            int4 ra = *(const int4*)&rows[e0];
            int4 rb2 = *(const int4*)&rows[e0 + 4];
            int4 ca = *(const int4*)&cols[e0];
            int4 cb = *(const int4*)&cols[e0 + 4];
            float4 va = *(const float4*)&vals[e0];
            float4 vb = *(const float4*)&vals[e0 + 4];
            int   r[8] = {ra.x, ra.y, ra.z, ra.w, rb2.x, rb2.y, rb2.z, rb2.w};
            int   c[8] = {ca.x, ca.y, ca.z, ca.w, cb.x, cb.y, cb.z, cb.w};
            float v[8] = {va.x, va.y, va.z, va.w, vb.x, vb.y, vb.z, vb.w};
            #pragma unroll
            for (int u = 0; u < 8; u++) {
                int p = atomicAdd(&cnt[r[u]], 1);
                unsigned pk = ((unsigned)c[u] << 16) |
                              (unsigned)__half_as_ushort(__float2half_rn(v[u]));
                cvp[(r[u] << 6) + p] = pk;
            }
        }
    } else {
        int NB = gridDim.x - EB;
        for (int g = ((b - EB) << 8) + t; g < 800000; g += (NB << 8)) {
            int base = g * 16;
            float4 f0 = *(const float4*)&x[base];
            float4 f1 = *(const float4*)&x[base + 4];
            float4 f2 = *(const float4*)&x[base + 8];
            float4 f3 = *(const float4*)&x[base + 12];
            short8 o0, o1;
            o0[0] = (short)f2bf(f0.x); o0[1] = (short)f2bf(f0.y);
            o0[2] = (short)f2bf(f0.z); o0[3] = (short)f2bf(f0.w);
            o0[4] = (short)f2bf(f1.x); o0[5] = (short)f2bf(f1.y);
            o0[6] = (short)f2bf(f1.z); o0[7] = (short)f2bf(f1.w);
            o1[0] = (short)f2bf(f2.x); o1[1] = (short)f2bf(f2.y);
            o1[2] = (short)f2bf(f2.z); o1[3] = (short)f2bf(f2.w);
            o1[4] = (short)f2bf(f3.x); o1[5] = (short)f2bf(f3.y);
            o1[6] = (short)f2bf(f3.z); o1[7] = (short)f2bf(f3.w);
            *(short8*)&bufH[base] = o0;
            *(short8*)&bufH[base + 8] = o1;
        }
    }
    gsync(bar);

    // ---- p2..p7 ----
    gemm256_phase(smem, bufH, Wt1, bufG);
    gsync(bar);
    spmm_phase<256, true, true>(bufG, cnt, cvp, b1, bufH);
    gsync(bar);
    gemm256_phase(smem, bufH, Wt2, bufG);
    gsync(bar);
    spmm_phase<256, true, true>(bufG, cnt, cvp, b2, bufH);
    gsync(bar);
    gemm128_phase(smem, bufH, Wt3, bufG);
    gsync(bar);
    spmm_phase<128, false, false>(bufG, cnt, cvp, b3, out);
}

// ---------------- launch ----------------

extern "C" void kernel_launch(void* const* d_in, const int* in_sizes, int n_in,
                              void* d_out, int out_size, void* d_ws, size_t ws_size,
                              hipStream_t stream) {
    const float* x    = (const float*)d_in[0];
    const float* av   = (const float*)d_in[1];
    const int*   rows = (const int*)d_in[2];
    const int*   cols = (const int*)d_in[3];
    const float* W1   = (const float*)d_in[4];
    const float* b1   = (const float*)d_in[5];
    const float* W2   = (const float*)d_in[6];
    const float* b2   = (const float*)d_in[7];
    const float* W3   = (const float*)d_in[8];
    const float* b3   = (const float*)d_in[9];
    float* out = (float*)d_out;

    const int N = N_NODES;

    char* p = (char*)d_ws;
    auto carve = [&](size_t bytes) {
        void* q = (void*)p;
        p += (bytes + 255) & ~(size_t)255;
        return q;
    };
    ushort*   bufG = (ushort*)carve((size_t)N * 256 * 2);
    ushort*   bufH = (ushort*)carve((size_t)N * 256 * 2);
    ushort*   Wt1  = (ushort*)carve((size_t)256 * 256 * 2);
    ushort*   Wt2  = (ushort*)carve((size_t)256 * 256 * 2);
    ushort*   Wt3  = (ushort*)carve((size_t)128 * 256 * 2);
    int*      cnt  = (int*)carve((size_t)50048 * 4);
    unsigned* cvp  = (unsigned*)carve(((size_t)N * ELLCAP + 128) * 4);
    unsigned* bar  = (unsigned*)carve(256);

    // deadlock-safe grid: occupancy query (cached), 8-CU safety margin
    static int nblk = 0;
    if (nblk == 0) {
        int occ = 0;
        if (hipOccupancyMaxActiveBlocksPerMultiprocessor(
                &occ, (const void*)fused_gcn, 256, 0) != hipSuccess || occ < 1)
            occ = 1;
        long nb = (long)occ * 248;
        if (nb > 744) nb = 744;
        if (nb < 248) nb = 248;
        nblk = (int)nb;
    }

    hipMemsetAsync(bar, 0, 16, stream);
    fused_gcn<<<nblk, 256, 0, stream>>>(
        x, av, rows, cols, W1, b1, W2, b2, W3, b3, out,
        bufG, bufH, Wt1, Wt2, Wt3, cnt, cvp, bar);
}

// Round 9
// 798.236 us; speedup vs baseline: 1.3603x; 1.3603x over previous
//
#include <hip/hip_runtime.h>
#include <hip/hip_fp16.h>

// GCN R12: prep/spmm = R9 verbatim (363us verified). GEMM replaced by a
// B-stationary design: whole Wt (128KB for 256 cols / 64KB for 128) staged
// once into LDS per block (1024 thr = 16 waves, 1 block/CU), ONE barrier;
// each wave then independently computes 16-row stripes with direct
// global->VGPR A fragments (no in-loop barriers at all). Swapped-operand
// MFMA (mfma(b,a)) puts A-rows on lane&15 -> each lane holds 4 consecutive
// output cols -> packed 8B coalesced C stores.

#define N_NODES 50000
#define N_EDGES 800000
#define KDIM 256
#define ELLCAP 64
#define ELLB 391             // 391*256*8 >= 800000 edges (8 edges/thread)
#define XCB 3125             // x-cast blocks: 3125*256*16 = 12.8M elems
#define TRB 640              // transpose blocks: 640*256 = 163840 ids

typedef __attribute__((ext_vector_type(8))) short short8;
typedef __attribute__((ext_vector_type(4))) short short4v;
typedef __attribute__((ext_vector_type(4))) float f32x4;

__device__ __forceinline__ ushort f2bf(float f) {
    union { float f; unsigned u; } x; x.f = f;
    unsigned r = x.u + 0x7fffu + ((x.u >> 16) & 1u);  // RTN-even
    return (ushort)(r >> 16);
}
__device__ __forceinline__ float bf2f(ushort u) {
    union { unsigned u; float f; } x; x.u = ((unsigned)u) << 16;
    return x.f;
}

__device__ __forceinline__ void gld_lds16(const void* g, void* l) {
    __builtin_amdgcn_global_load_lds(
        (const __attribute__((address_space(1))) void*)g,
        (__attribute__((address_space(3))) void*)l, 16, 0, 0);
}

// ---------------- prep: ELL build + x->bf16 cast + weight transposes ------
// (byte-identical to R9)
__global__ __launch_bounds__(256) void prep_kernel(
        const float* __restrict__ W1, const float* __restrict__ W2,
        const float* __restrict__ W3, ushort* __restrict__ Wt1,
        ushort* __restrict__ Wt2, ushort* __restrict__ Wt3,
        const int* __restrict__ rows, const int* __restrict__ cols,
        const float* __restrict__ vals, int* __restrict__ cnt,
        unsigned* __restrict__ cvp, const float* __restrict__ x,
        ushort* __restrict__ bufX) {
    int b = blockIdx.x;
    if (b < ELLB) {
        int e0 = (b * 256 + threadIdx.x) * 8;
        if (e0 < N_EDGES) {           // N_EDGES % 8 == 0: full oct or skip
            int4 ra = *(const int4*)&rows[e0];
            int4 rb = *(const int4*)&rows[e0 + 4];
            int4 ca = *(const int4*)&cols[e0];
            int4 cb = *(const int4*)&cols[e0 + 4];
            float4 va = *(const float4*)&vals[e0];
            float4 vb = *(const float4*)&vals[e0 + 4];
            int   r[8] = {ra.x, ra.y, ra.z, ra.w, rb.x, rb.y, rb.z, rb.w};
            int   c[8] = {ca.x, ca.y, ca.z, ca.w, cb.x, cb.y, cb.z, cb.w};
            float v[8] = {va.x, va.y, va.z, va.w, vb.x, vb.y, vb.z, vb.w};
            #pragma unroll
            for (int u = 0; u < 8; u++) {
                int p = atomicAdd(&cnt[r[u]], 1);
                unsigned pk = ((unsigned)c[u] << 16) |
                              (unsigned)__half_as_ushort(__float2half_rn(v[u]));
                cvp[(r[u] << 6) + p] = pk;
            }
        }
    } else if (b < ELLB + XCB) {
        int base = ((b - ELLB) * 256 + threadIdx.x) * 16;  // exact coverage
        float4 f0 = *(const float4*)&x[base];
        float4 f1 = *(const float4*)&x[base + 4];
        float4 f2 = *(const float4*)&x[base + 8];
        float4 f3 = *(const float4*)&x[base + 12];
        short8 o0, o1;
        o0[0] = (short)f2bf(f0.x); o0[1] = (short)f2bf(f0.y);
        o0[2] = (short)f2bf(f0.z); o0[3] = (short)f2bf(f0.w);
        o0[4] = (short)f2bf(f1.x); o0[5] = (short)f2bf(f1.y);
        o0[6] = (short)f2bf(f1.z); o0[7] = (short)f2bf(f1.w);
        o1[0] = (short)f2bf(f2.x); o1[1] = (short)f2bf(f2.y);
        o1[2] = (short)f2bf(f2.z); o1[3] = (short)f2bf(f2.w);
        o1[4] = (short)f2bf(f3.x); o1[5] = (short)f2bf(f3.y);
        o1[6] = (short)f2bf(f3.z); o1[7] = (short)f2bf(f3.w);
        *(short8*)&bufX[base] = o0;
        *(short8*)&bufX[base + 8] = o1;
    } else {
        int id = (b - ELLB - XCB) * 256 + threadIdx.x;
        if (id < 65536) {
            int n = id >> 8, k = id & 255;
            Wt1[n * 256 + k] = f2bf(W1[k * 256 + n]);
        } else if (id < 131072) {
            int i = id - 65536, n = i >> 8, k = i & 255;
            Wt2[n * 256 + k] = f2bf(W2[k * 256 + n]);
        } else {
            int i = id - 131072, n = i >> 8, k = i & 255;
            Wt3[n * 256 + k] = f2bf(W3[k * 128 + n]);
        }
    }
}

// ---------------- GEMM, B-stationary: C[M,NC] = A[M,256] @ Wt[NC,256]^T ----
// Block = 1024 thr (16 waves), LDS = whole Wt, frag-major granules:
//   granule g = (ct*8 + kt)*64 + l  holds Wt[ct*16 + (l&15)][kt*32+(l>>4)*8..+8]
// Stage once (global_load_lds, linear dest, permuted src), one barrier.
// Each wave owns 16-row stripes: af[kt] = A[r0+mi][kt*32+q*8..+8] direct from
// global; acc[ct] = sum_kt mfma(bfr[ct][kt], af[kt]) -> lane holds
// C[r0+mi][ct*16+q*4 .. +4] -> packed short4 store (coalesced 32B/row).

template <int NC>
__global__ __launch_bounds__(1024, 4) void gemm_bls_kernel(
        const ushort* __restrict__ A, const ushort* __restrict__ Wt,
        ushort* __restrict__ C) {
    constexpr int CT = NC / 16;            // 16 or 8 col-tiles
    constexpr int GR = CT * 8 * 64;        // granule count: 8192 / 4096
    __shared__ char Bs[GR * 16];           // 128KB / 64KB

    int t = threadIdx.x, lane = t & 63, w = t >> 6;
    int q = lane >> 4, mi = lane & 15;

    // ---- stage whole Wt into LDS ----
    #pragma unroll
    for (int i = 0; i < GR / 1024; i++) {
        int g = i * 1024 + t;
        int ct = g >> 9, kt = (g >> 6) & 7, l = g & 63;
        const ushort* src = Wt + (size_t)(ct * 16 + (l & 15)) * KDIM
                               + kt * 32 + ((l >> 4) << 3);
        gld_lds16(src, Bs + (i * 1024 + w * 64) * 16);
    }
    __syncthreads();                       // vmcnt(0) drained: Bs ready

    // ---- per-wave independent 16-row stripes (no barriers) ----
    int nw = gridDim.x << 4;               // total waves
    for (int s = (blockIdx.x << 4) + w; s < N_NODES / 16; s += nw) {
        int r0 = s * 16;
        const ushort* Ar = A + (size_t)(r0 + mi) * KDIM + (q << 3);
        short8 af[8];
        #pragma unroll
        for (int kt = 0; kt < 8; kt++)
            af[kt] = *(const short8*)(Ar + kt * 32);

        #pragma unroll
        for (int ct = 0; ct < CT; ct++) {
            f32x4 acc = (f32x4)0.f;
            #pragma unroll
            for (int kt = 0; kt < 8; kt++) {
                short8 bfr = *(const short8*)(Bs + (((ct * 8 + kt) << 6) + lane) * 16);
                acc = __builtin_amdgcn_mfma_f32_16x16x32_bf16(bfr, af[kt], acc, 0, 0, 0);
            }
            short4v o;
            o[0] = (short)f2bf(acc[0]); o[1] = (short)f2bf(acc[1]);
            o[2] = (short)f2bf(acc[2]); o[3] = (short)f2bf(acc[3]);
            *(short4v*)&C[(size_t)(r0 + mi) * NC + ct * 16 + (q << 2)] = o;
        }
    }
}

// ---------------- SpMM (ELL, packed 4B meta): wave/row, 8-deep gathers ----
// (byte-identical to R9)
template <int F, bool RELU, bool OUT_BF16>
__global__ __launch_bounds__(256) void spmm_kernel(
        const ushort* __restrict__ H, const int* __restrict__ cnt,
        const unsigned* __restrict__ cvp, const float* __restrict__ bias,
        void* __restrict__ out, int nrows) {
    constexpr int FL = F / 8;       // 32 (F=256) / 16 (F=128)
    constexpr int EP = 64 / FL;     // 2 / 4
    constexpr int STEP = EP * 8;    // 16 / 32 edges per iteration
    int wave = threadIdx.x >> 6, lane = threadIdx.x & 63;
    int r = blockIdx.x * 4 + wave;
    if (r >= nrows) return;
    int fl = lane % FL, ep = lane / FL;
    const ushort* Hl = H + fl * 8;

    float acc[8];
    #pragma unroll
    for (int j = 0; j < 8; j++) acc[j] = 0.f;

    int start = r << 6;             // ELLCAP = 64
    int end = start + cnt[r];
    for (int base = start; base < end; base += STEP) {
        int e0 = base + ep * 8;     // 32B-aligned into cvp
        uint4 ma = *(const uint4*)&cvp[e0];
        uint4 mb = *(const uint4*)&cvp[e0 + 4];
        unsigned mw[8] = {ma.x, ma.y, ma.z, ma.w, mb.x, mb.y, mb.z, mb.w};
        int   c[8];
        float v[8];
        #pragma unroll
        for (int u = 0; u < 8; u++) {
            bool ok = (e0 + u < end);
            c[u] = ok ? (int)(mw[u] >> 16) : 0;
            v[u] = ok ? __half2float(__ushort_as_half((ushort)mw[u])) : 0.f;
        }
        short8 h[8];
        #pragma unroll
        for (int u = 0; u < 8; u++)
            h[u] = *(const short8*)&Hl[(size_t)c[u] * F];
        #pragma unroll
        for (int j = 0; j < 8; j++) {
            #pragma unroll
            for (int u = 0; u < 8; u++)
                acc[j] += v[u] * bf2f((ushort)h[u][j]);
        }
    }

    #pragma unroll
    for (int off = FL; off < 64; off <<= 1)
        #pragma unroll
        for (int j = 0; j < 8; j++) acc[j] += __shfl_down(acc[j], off, 64);

    if (ep == 0) {
        #pragma unroll
        for (int j = 0; j < 8; j++) {
            float o = acc[j] + bias[fl * 8 + j];
            if (RELU) o = fmaxf(o, 0.f);
            acc[j] = o;
        }
        if (OUT_BF16) {
            short8 ob;
            #pragma unroll
            for (int j = 0; j < 8; j++) ob[j] = (short)f2bf(acc[j]);
            *(short8*)((ushort*)out + (size_t)r * F + fl * 8) = ob;
        } else {
            float* of = (float*)out + (size_t)r * F + fl * 8;
            *(float4*)&of[0] = make_float4(acc[0], acc[1], acc[2], acc[3]);
            *(float4*)&of[4] = make_float4(acc[4], acc[5], acc[6], acc[7]);
        }
    }
}

// ---------------- launch ----------------

extern "C" void kernel_launch(void* const* d_in, const int* in_sizes, int n_in,
                              void* d_out, int out_size, void* d_ws, size_t ws_size,
                              hipStream_t stream) {
    const float* x    = (const float*)d_in[0];
    const float* av   = (const float*)d_in[1];
    const int*   rows = (const int*)d_in[2];
    const int*   cols = (const int*)d_in[3];
    const float* W1   = (const float*)d_in[4];
    const float* b1   = (const float*)d_in[5];
    const float* W2   = (const float*)d_in[6];
    const float* b2   = (const float*)d_in[7];
    const float* W3   = (const float*)d_in[8];
    const float* b3   = (const float*)d_in[9];
    float* out = (float*)d_out;

    const int N = N_NODES;

    char* p = (char*)d_ws;
    auto carve = [&](size_t bytes) {
        void* q = (void*)p;
        p += (bytes + 255) & ~(size_t)255;
        return q;
    };
    ushort*   bufG = (ushort*)carve((size_t)N * 256 * 2);
    ushort*   bufH = (ushort*)carve((size_t)N * 256 * 2);
    ushort*   Wt1  = (ushort*)carve((size_t)256 * 256 * 2);
    ushort*   Wt2  = (ushort*)carve((size_t)256 * 256 * 2);
    ushort*   Wt3  = (ushort*)carve((size_t)128 * 256 * 2);
    int*      cnt  = (int*)carve((size_t)N * 4);
    unsigned* cvp  = (unsigned*)carve(((size_t)N * ELLCAP + 128) * 4);

    hipMemsetAsync(cnt, 0, (size_t)N * 4, stream);

    // ELL build + x cast (into bufH) + weight transposes, one fat kernel
    prep_kernel<<<ELLB + XCB + TRB, 256, 0, stream>>>(
        W1, W2, W3, Wt1, Wt2, Wt3, rows, cols, av, cnt, cvp, x, bufH);

    int spmm_blocks = (N + 3) / 4;
    gemm_bls_kernel<256><<<256, 1024, 0, stream>>>(bufH, Wt1, bufG);
    spmm_kernel<256, true, true><<<spmm_blocks, 256, 0, stream>>>(bufG, cnt, cvp, b1, bufH, N);
    gemm_bls_kernel<256><<<256, 1024, 0, stream>>>(bufH, Wt2, bufG);
    spmm_kernel<256, true, true><<<spmm_blocks, 256, 0, stream>>>(bufG, cnt, cvp, b2, bufH, N);
    gemm_bls_kernel<128><<<256, 1024, 0, stream>>>(bufH, Wt3, bufG);
    spmm_kernel<128, false, false><<<spmm_blocks, 256, 0, stream>>>(bufG, cnt, cvp, b3, out, N);
}

// Round 10
// 342.397 us; speedup vs baseline: 3.1714x; 2.3313x over previous
//
#include <hip/hip_runtime.h>
#include <hip/hip_fp16.h>

// GCN R13: R9 base (363us verified: prep + gemm1 + spmm3 byte-identical).
// The two middle {spmm -> gemm} pairs are fused block-level: one block
// spmm-computes 64 rows (wave-per-row x4, 4-deep gathers) directly INTO the
// frag-major LDS A-tile (kt-XOR swizzle: conflict-free reads, 4-way writes),
// then gemms those rows against L2-hot Wt (B dbuf prefetched under the spmm
// phase). Kills 2 dispatches + 2x25.6MB H writes + 2x25.6MB A reads, and the
// gemm A-staging latency entirely. C stores stay LDS-staged full-row
// coalesced (R12 lesson: scattered small stores = 14x write amplification).

#define N_NODES 50000
#define N_EDGES 800000
#define KDIM 256
#define BK 32
#define ELLCAP 64
#define ELLB 391             // 391*256*8 >= 800000 edges (8 edges/thread)
#define XCB 3125             // x-cast blocks: 3125*256*16 = 12.8M elems
#define TRB 640              // transpose blocks: 640*256 = 163840 ids

typedef __attribute__((ext_vector_type(8))) short short8;
typedef __attribute__((ext_vector_type(4))) float f32x4;

__device__ __forceinline__ ushort f2bf(float f) {
    union { float f; unsigned u; } x; x.f = f;
    unsigned r = x.u + 0x7fffu + ((x.u >> 16) & 1u);  // RTN-even
    return (ushort)(r >> 16);
}
__device__ __forceinline__ float bf2f(ushort u) {
    union { unsigned u; float f; } x; x.u = ((unsigned)u) << 16;
    return x.f;
}

__device__ __forceinline__ void gld_lds16(const void* g, void* l) {
    __builtin_amdgcn_global_load_lds(
        (const __attribute__((address_space(1))) void*)g,
        (__attribute__((address_space(3))) void*)l, 16, 0, 0);
}

// ---------------- prep: ELL build + x->bf16 cast + weight transposes ------
// (byte-identical to R9)
__global__ __launch_bounds__(256) void prep_kernel(
        const float* __restrict__ W1, const float* __restrict__ W2,
        const float* __restrict__ W3, ushort* __restrict__ Wt1,
        ushort* __restrict__ Wt2, ushort* __restrict__ Wt3,
        const int* __restrict__ rows, const int* __restrict__ cols,
        const float* __restrict__ vals, int* __restrict__ cnt,
        unsigned* __restrict__ cvp, const float* __restrict__ x,
        ushort* __restrict__ bufX) {
    int b = blockIdx.x;
    if (b < ELLB) {
        int e0 = (b * 256 + threadIdx.x) * 8;
        if (e0 < N_EDGES) {           // N_EDGES % 8 == 0: full oct or skip
            int4 ra = *(const int4*)&rows[e0];
            int4 rb = *(const int4*)&rows[e0 + 4];
            int4 ca = *(const int4*)&cols[e0];
            int4 cb = *(const int4*)&cols[e0 + 4];
            float4 va = *(const float4*)&vals[e0];
            float4 vb = *(const float4*)&vals[e0 + 4];
            int   r[8] = {ra.x, ra.y, ra.z, ra.w, rb.x, rb.y, rb.z, rb.w};
            int   c[8] = {ca.x, ca.y, ca.z, ca.w, cb.x, cb.y, cb.z, cb.w};
            float v[8] = {va.x, va.y, va.z, va.w, vb.x, vb.y, vb.z, vb.w};
            #pragma unroll
            for (int u = 0; u < 8; u++) {
                int p = atomicAdd(&cnt[r[u]], 1);
                unsigned pk = ((unsigned)c[u] << 16) |
                              (unsigned)__half_as_ushort(__float2half_rn(v[u]));
                cvp[(r[u] << 6) + p] = pk;
            }
        }
    } else if (b < ELLB + XCB) {
        int base = ((b - ELLB) * 256 + threadIdx.x) * 16;  // exact coverage
        float4 f0 = *(const float4*)&x[base];
        float4 f1 = *(const float4*)&x[base + 4];
        float4 f2 = *(const float4*)&x[base + 8];
        float4 f3 = *(const float4*)&x[base + 12];
        short8 o0, o1;
        o0[0] = (short)f2bf(f0.x); o0[1] = (short)f2bf(f0.y);
        o0[2] = (short)f2bf(f0.z); o0[3] = (short)f2bf(f0.w);
        o0[4] = (short)f2bf(f1.x); o0[5] = (short)f2bf(f1.y);
        o0[6] = (short)f2bf(f1.z); o0[7] = (short)f2bf(f1.w);
        o1[0] = (short)f2bf(f2.x); o1[1] = (short)f2bf(f2.y);
        o1[2] = (short)f2bf(f2.z); o1[3] = (short)f2bf(f2.w);
        o1[4] = (short)f2bf(f3.x); o1[5] = (short)f2bf(f3.y);
        o1[6] = (short)f2bf(f3.z); o1[7] = (short)f2bf(f3.w);
        *(short8*)&bufX[base] = o0;
        *(short8*)&bufX[base + 8] = o1;
    } else {
        int id = (b - ELLB - XCB) * 256 + threadIdx.x;
        if (id < 65536) {
            int n = id >> 8, k = id & 255;
            Wt1[n * 256 + k] = f2bf(W1[k * 256 + n]);
        } else if (id < 131072) {
            int i = id - 65536, n = i >> 8, k = i & 255;
            Wt2[n * 256 + k] = f2bf(W2[k * 256 + n]);
        } else {
            int i = id - 131072, n = i >> 8, k = i & 255;
            Wt3[n * 256 + k] = f2bf(W3[k * 128 + n]);
        }
    }
}

// ---------------- GEMM1 (byte-identical to R9 gemm_rows_kernel) -----------
template <int N>
__global__ __launch_bounds__(N, 2) void gemm_rows_kernel(
        const ushort* __restrict__ A, const ushort* __restrict__ Wt,
        ushort* __restrict__ C, int M) {
    __shared__ char smem[32768 + 2 * N * 64];   // A panel + B dbuf

    int t = threadIdx.x;
    int lane = t & 63;
    int w = t >> 6;
    int row0 = blockIdx.x * 64;
    int wn = w * 64;
    int q = lane >> 4, mi = lane & 15;

    #pragma unroll
    for (int i = 0; i < 2048 / N; i++) {
        int g = i * N + t;
        int kt = g >> 8, mt = (g >> 6) & 3, l = g & 63;
        int row = row0 + mt * 16 + (l & 15);
        if (row >= M) row = M - 1;
        const ushort* src = A + (size_t)row * KDIM + kt * 32 + ((l >> 4) << 3);
        gld_lds16(src, smem + (i * N + w * 64) * 16);
    }

    auto stageB = [&](int bi, int k0) {
        char* dst = smem + 32768 + bi * (N * 64);
        #pragma unroll
        for (int i = 0; i < 4; i++) {
            int g = i * N + t;
            int col = ((g >> 6) << 4) + (g & 15);
            const ushort* src = Wt + (size_t)col * KDIM + k0 + (((g & 63) >> 4) << 3);
            gld_lds16(src, dst + (i * N + w * 64) * 16);
        }
    };

    f32x4 acc[4][4];
    #pragma unroll
    for (int i = 0; i < 4; i++)
        #pragma unroll
        for (int j = 0; j < 4; j++) acc[i][j] = (f32x4)0.f;

    stageB(0, 0);
    __syncthreads();

    #pragma unroll
    for (int kt = 0; kt < 8; kt++) {
        int cur = kt & 1;
        if (kt < 7) stageB(cur ^ 1, (kt + 1) * BK);

        const char* Bc = smem + 32768 + cur * (N * 64);
        short8 af[4], bfr[4];
        #pragma unroll
        for (int mt = 0; mt < 4; mt++)
            af[mt] = *(const short8*)(smem + ((kt * 4 + mt) * 64 + lane) * 16);
        #pragma unroll
        for (int nt = 0; nt < 4; nt++)
            bfr[nt] = *(const short8*)(Bc + ((w * 4 + nt) * 64 + lane) * 16);

        #pragma unroll
        for (int mt = 0; mt < 4; mt++)
            #pragma unroll
            for (int nt = 0; nt < 4; nt++)
                acc[mt][nt] = __builtin_amdgcn_mfma_f32_16x16x32_bf16(
                    af[mt], bfr[nt], acc[mt][nt], 0, 0, 0);

        __syncthreads();
    }

    ushort* Cs = (ushort*)smem;
    #pragma unroll
    for (int mt = 0; mt < 4; mt++)
        #pragma unroll
        for (int r = 0; r < 4; r++)
            #pragma unroll
            for (int nt = 0; nt < 4; nt++)
                Cs[(mt * 16 + q * 4 + r) * N + wn + nt * 16 + mi] =
                    f2bf(acc[mt][nt][r]);
    __syncthreads();
    constexpr int C8 = N / 8;
    #pragma unroll
    for (int i = 0; i < 8; i++) {
        int idx = i * N + t;
        int rr = idx / C8, gc = idx % C8;
        int grow = row0 + rr;
        if (grow < M)
            *(short8*)&C[(size_t)grow * N + gc * 8] =
                *(const short8*)&Cs[rr * N + gc * 8];
    }
}

// ---------------- fused SpMM+GEMM ------------------------------------------
// Block: 1024 thr (16 waves), 64 rows. Phase A: wave w spmm-computes rows
// w*4..w*4+3 (FL=32 lanes over 256 cols, 2 edge-groups x 4-deep gathers),
// +bias, ReLU, bf16-pack, ds_write into frag-major A slot:
//   slot = (kt*4+mt)*64 + q*16 + mi  for  A[r0+mt*16+mi][kt*32+q*8..+8]
//   byte = slot*16 ^ ((slot>>8)<<4)  (kt-XOR: reads conflict-free, writes 4-way)
// Phase B: wave w owns col-tile ct=w%CT, m-half mh=w/CT; per kt: 1 bfr +
// MTW af ds_reads + MTW MFMA; B dbuf (L2-hot Wt), B0 prefetched under
// phase A. Epilogue: LDS-staged C, full-row coalesced stores.

template <int NOUT>
__global__ __launch_bounds__(1024, 8) void spmm_gemm_kernel(
        const ushort* __restrict__ H, const int* __restrict__ cnt,
        const unsigned* __restrict__ cvp, const float* __restrict__ bias,
        const ushort* __restrict__ Wt, ushort* __restrict__ C) {
    __shared__ char smem[32768 + 2 * NOUT * 64];
    int t = threadIdx.x, lane = t & 63, w = t >> 6;
    int q = lane >> 4, mi = lane & 15;
    int r0 = blockIdx.x * 64;

    auto stageB = [&](int bi, int k0) {
        if (w < NOUT / 16) {                 // wave-uniform guard
            char* dst = smem + 32768 + bi * (NOUT * 64) + (w * 64) * 16;
            int g = t;                       // granule = w*64 + lane
            int col = ((g >> 6) << 4) + (g & 15);
            const ushort* src = Wt + (size_t)col * KDIM + k0 + (((g & 63) >> 4) << 3);
            gld_lds16(src, dst);
        }
    };

    stageB(0, 0);                            // B0 flies under the spmm phase

    // ---- phase A: spmm rows r0..r0+63 into frag-major A tile ----
    {
        const int fl = lane & 31, ep = lane >> 5;
        const ushort* Hl = H + fl * 8;
        #pragma unroll 1
        for (int i = 0; i < 4; i++) {
            int rr = w * 4 + i;
            int r = r0 + rr;
            float acc[8];
            #pragma unroll
            for (int j = 0; j < 8; j++) acc[j] = 0.f;
            if (r < N_NODES) {
                int start = r << 6, end = start + cnt[r];
                for (int base = start; base < end; base += 8) {
                    int e0 = base + ep * 4;          // 16B-aligned
                    uint4 ma = *(const uint4*)&cvp[e0];
                    unsigned mw[4] = {ma.x, ma.y, ma.z, ma.w};
                    int c4[4]; float v4[4];
                    #pragma unroll
                    for (int u = 0; u < 4; u++) {
                        bool ok = (e0 + u < end);
                        c4[u] = ok ? (int)(mw[u] >> 16) : 0;
                        v4[u] = ok ? __half2float(__ushort_as_half((ushort)mw[u])) : 0.f;
                    }
                    short8 h4[4];
                    #pragma unroll
                    for (int u = 0; u < 4; u++)
                        h4[u] = *(const short8*)&Hl[(size_t)c4[u] * 256];
                    #pragma unroll
                    for (int j = 0; j < 8; j++)
                        acc[j] += v4[0] * bf2f((ushort)h4[0][j])
                                + v4[1] * bf2f((ushort)h4[1][j])
                                + v4[2] * bf2f((ushort)h4[2][j])
                                + v4[3] * bf2f((ushort)h4[3][j]);
                }
            }
            #pragma unroll
            for (int j = 0; j < 8; j++) acc[j] += __shfl_down(acc[j], 32, 64);
            if (ep == 0) {
                short8 ob;
                #pragma unroll
                for (int j = 0; j < 8; j++) {
                    float o = fmaxf(acc[j] + bias[fl * 8 + j], 0.f);
                    ob[j] = (short)f2bf(o);
                }
                int slot = ((fl >> 2) * 4 + (rr >> 4)) * 64 + (fl & 3) * 16 + (rr & 15);
                int byt = (slot * 16) ^ (((slot >> 8) & 7) << 4);
                *(short8*)(smem + byt) = ob;
            }
        }
    }
    __syncthreads();                         // A tile + B0 ready

    // ---- phase B: gemm ----
    constexpr int CT = NOUT / 16;            // 16 / 8 col-tiles
    constexpr int MTW = CT / 4;              // 4 / 2 m-tiles per wave
    int ct = w % CT, mh = w / CT;
    f32x4 acc[MTW];
    #pragma unroll
    for (int m = 0; m < MTW; m++) acc[m] = (f32x4)0.f;

    #pragma unroll
    for (int kt = 0; kt < 8; kt++) {
        int cur = kt & 1;
        if (kt < 7) stageB(cur ^ 1, (kt + 1) * BK);
        const char* Bc = smem + 32768 + cur * (NOUT * 64);
        short8 bfr = *(const short8*)(Bc + (ct * 64 + lane) * 16);
        #pragma unroll
        for (int m = 0; m < MTW; m++) {
            int mt = mh * MTW + m;
            int slot = (kt * 4 + mt) * 64 + lane;
            int byt = (slot * 16) ^ ((kt & 7) << 4);
            short8 af = *(const short8*)(smem + byt);
            acc[m] = __builtin_amdgcn_mfma_f32_16x16x32_bf16(af, bfr, acc[m], 0, 0, 0);
        }
        __syncthreads();
    }

    // ---- epilogue: LDS-staged C, full-row coalesced stores ----
    ushort* Cs = (ushort*)smem;              // 64 x NOUT bf16 <= 32KB
    #pragma unroll
    for (int m = 0; m < MTW; m++) {
        int mt = mh * MTW + m;
        #pragma unroll
        for (int rg = 0; rg < 4; rg++)
            Cs[(mt * 16 + q * 4 + rg) * NOUT + ct * 16 + mi] = f2bf(acc[m][rg]);
    }
    __syncthreads();
    constexpr int C8 = NOUT / 8;
    #pragma unroll
    for (int i = 0; i < (64 * C8) / 1024; i++) {
        int idx = i * 1024 + t;
        int rr = idx / C8, gc = idx % C8;
        int grow = r0 + rr;
        if (grow < N_NODES)
            *(short8*)&C[(size_t)grow * NOUT + gc * 8] =
                *(const short8*)&Cs[rr * NOUT + gc * 8];
    }
}

// ---------------- SpMM (byte-identical to R9) ------------------------------
template <int F, bool RELU, bool OUT_BF16>
__global__ __launch_bounds__(256) void spmm_kernel(
        const ushort* __restrict__ H, const int* __restrict__ cnt,
        const unsigned* __restrict__ cvp, const float* __restrict__ bias,
        void* __restrict__ out, int nrows) {
    constexpr int FL = F / 8;       // 32 (F=256) / 16 (F=128)
    constexpr int EP = 64 / FL;     // 2 / 4
    constexpr int STEP = EP * 8;    // 16 / 32 edges per iteration
    int wave = threadIdx.x >> 6, lane = threadIdx.x & 63;
    int r = blockIdx.x * 4 + wave;
    if (r >= nrows) return;
    int fl = lane % FL, ep = lane / FL;
    const ushort* Hl = H + fl * 8;

    float acc[8];
    #pragma unroll
    for (int j = 0; j < 8; j++) acc[j] = 0.f;

    int start = r << 6;             // ELLCAP = 64
    int end = start + cnt[r];
    for (int base = start; base < end; base += STEP) {
        int e0 = base + ep * 8;     // 32B-aligned into cvp
        uint4 ma = *(const uint4*)&cvp[e0];
        uint4 mb = *(const uint4*)&cvp[e0 + 4];
        unsigned mw[8] = {ma.x, ma.y, ma.z, ma.w, mb.x, mb.y, mb.z, mb.w};
        int   c[8];
        float v[8];
        #pragma unroll
        for (int u = 0; u < 8; u++) {
            bool ok = (e0 + u < end);
            c[u] = ok ? (int)(mw[u] >> 16) : 0;
            v[u] = ok ? __half2float(__ushort_as_half((ushort)mw[u])) : 0.f;
        }
        short8 h[8];
        #pragma unroll
        for (int u = 0; u < 8; u++)
            h[u] = *(const short8*)&Hl[(size_t)c[u] * F];
        #pragma unroll
        for (int j = 0; j < 8; j++) {
            #pragma unroll
            for (int u = 0; u < 8; u++)
                acc[j] += v[u] * bf2f((ushort)h[u][j]);
        }
    }

    #pragma unroll
    for (int off = FL; off < 64; off <<= 1)
        #pragma unroll
        for (int j = 0; j < 8; j++) acc[j] += __shfl_down(acc[j], off, 64);

    if (ep == 0) {
        #pragma unroll
        for (int j = 0; j < 8; j++) {
            float o = acc[j] + bias[fl * 8 + j];
            if (RELU) o = fmaxf(o, 0.f);
            acc[j] = o;
        }
        if (OUT_BF16) {
            short8 ob;
            #pragma unroll
            for (int j = 0; j < 8; j++) ob[j] = (short)f2bf(acc[j]);
            *(short8*)((ushort*)out + (size_t)r * F + fl * 8) = ob;
        } else {
            float* of = (float*)out + (size_t)r * F + fl * 8;
            *(float4*)&of[0] = make_float4(acc[0], acc[1], acc[2], acc[3]);
            *(float4*)&of[4] = make_float4(acc[4], acc[5], acc[6], acc[7]);
        }
    }
}

// ---------------- launch ----------------

extern "C" void kernel_launch(void* const* d_in, const int* in_sizes, int n_in,
                              void* d_out, int out_size, void* d_ws, size_t ws_size,
                              hipStream_t stream) {
    const float* x    = (const float*)d_in[0];
    const float* av   = (const float*)d_in[1];
    const int*   rows = (const int*)d_in[2];
    const int*   cols = (const int*)d_in[3];
    const float* W1   = (const float*)d_in[4];
    const float* b1   = (const float*)d_in[5];
    const float* W2   = (const float*)d_in[6];
    const float* b2   = (const float*)d_in[7];
    const float* W3   = (const float*)d_in[8];
    const float* b3   = (const float*)d_in[9];
    float* out = (float*)d_out;

    const int N = N_NODES;

    char* p = (char*)d_ws;
    auto carve = [&](size_t bytes) {
        void* q = (void*)p;
        p += (bytes + 255) & ~(size_t)255;
        return q;
    };
    ushort*   bufG = (ushort*)carve((size_t)N * 256 * 2);
    ushort*   bufH = (ushort*)carve((size_t)N * 256 * 2);
    ushort*   Wt1  = (ushort*)carve((size_t)256 * 256 * 2);
    ushort*   Wt2  = (ushort*)carve((size_t)256 * 256 * 2);
    ushort*   Wt3  = (ushort*)carve((size_t)128 * 256 * 2);
    int*      cnt  = (int*)carve((size_t)N * 4);
    unsigned* cvp  = (unsigned*)carve(((size_t)N * ELLCAP + 128) * 4);

    hipMemsetAsync(cnt, 0, (size_t)N * 4, stream);

    // prep: ELL build + x cast (into bufH) + weight transposes
    prep_kernel<<<ELLB + XCB + TRB, 256, 0, stream>>>(
        W1, W2, W3, Wt1, Wt2, Wt3, rows, cols, av, cnt, cvp, x, bufH);

    // gemm1: bufH(bf16 x) @ W1 -> bufG
    gemm_rows_kernel<256><<<782, 256, 0, stream>>>(bufH, Wt1, bufG, N);

    // fused: h1 = relu(adj@bufG + b1); bufH = h1 @ W2
    spmm_gemm_kernel<256><<<782, 1024, 0, stream>>>(bufG, cnt, cvp, b1, Wt2, bufH);
    // fused: h2 = relu(adj@bufH + b2); bufG = h2 @ W3  (128 cols)
    spmm_gemm_kernel<128><<<782, 1024, 0, stream>>>(bufH, cnt, cvp, b2, Wt3, bufG);

    // spmm3: out = adj@bufG + b3 (fp32)
    spmm_kernel<128, false, false><<<(N + 3) / 4, 256, 0, stream>>>(
        bufG, cnt, cvp, b3, out, N);
}